// Round 5
// baseline (493.143 us; speedup 1.0000x reference)
//
#include <hip/hip_runtime.h>
#include <hip/hip_bf16.h>
#include <stdint.h>

#define SS 1024
#define DD 128
#define TQ 128          // q rows per block
#define TK 64           // kv cols per tile
#define NKT (SS/TK)     // 16
#define THREADS 512     // 8 waves
#define NHEAD 128
#define LOG2E 1.44269504088896340736f
#define DEFER_THR 11.5415603f   // 8 * log2e

typedef short bf16x8 __attribute__((ext_vector_type(8)));
typedef float f32x4  __attribute__((ext_vector_type(4)));

// ---------------- threefry2x32, key = (0, 42) — bit-exact (R1) -------------
__device__ __forceinline__ uint32_t rotl32(uint32_t v, uint32_t s) {
#if __has_builtin(__builtin_rotateleft32)
  return __builtin_rotateleft32(v, s);   // v_alignbit_b32
#else
  return (v << s) | (v >> (32u - s));
#endif
}
__device__ __forceinline__ uint32_t threefry_bits(uint32_t ctr) {
  const uint32_t K0 = 0u, K1 = 42u;
  const uint32_t K2 = K0 ^ K1 ^ 0x1BD11BDAu;
  uint32_t x0 = K0;
  uint32_t x1 = ctr + K1;
#define TF_RND(r) { x0 += x1; x1 = rotl32(x1, r); x1 ^= x0; }
  TF_RND(13u) TF_RND(15u) TF_RND(26u) TF_RND(6u)
  x0 += K1; x1 += K2 + 1u;
  TF_RND(17u) TF_RND(29u) TF_RND(16u) TF_RND(24u)
  x0 += K2; x1 += K0 + 2u;
  TF_RND(13u) TF_RND(15u) TF_RND(26u) TF_RND(6u)
  x0 += K0; x1 += K1 + 3u;
  TF_RND(17u) TF_RND(29u) TF_RND(16u) TF_RND(24u)
  x0 += K1; x1 += K2 + 4u;
  TF_RND(13u) TF_RND(15u) TF_RND(26u) TF_RND(6u)
  x0 += K2; x1 += K0 + 5u;
#undef TF_RND
  return x0 ^ x1;
}
// 16 keep-bits starting at element counter `base` (bit b: uniform < 0.9f)
__device__ __forceinline__ uint32_t maskhalf(uint32_t base) {
  uint32_t h = 0u;
#pragma unroll 4
  for (int b = 0; b < 16; ++b)
    h |= (threefry_bits(base + (uint32_t)b) < 0xE6666600u) ? (1u << b) : 0u;
  return h;
}

// ---------------- bf16 helpers --------------------------------------------
__device__ __forceinline__ short f2bf(float x) {
  return __builtin_bit_cast(short, __float2bfloat16(x));   // RNE
}
__device__ __forceinline__ float bf2f(short b) {
  return __uint_as_float(((uint32_t)(uint16_t)b) << 16);
}
__device__ __forceinline__ uint32_t pack2(short a, short b) {
  return (uint32_t)(uint16_t)a | ((uint32_t)(uint16_t)b << 16);
}
__device__ __forceinline__ void split2(float x, short& hi, short& lo) {
  hi = f2bf(x);
  lo = f2bf(x - bf2f(hi));
}

#define MFMA16(A, B, C) __builtin_amdgcn_mfma_f32_16x16x32_bf16(A, B, C, 0, 0, 0)

// LDS layout (shorts):
//  Khi[64][136] @0, Klo[64][136] @8704,
//  Vt[128][72] @17408, Pt[128][72] @26624,
//  Ms: ushort[2][512] @35840 (double-buffered dropout half-words)
#define SMEM_SHORTS 36864

// LDS (72 KiB) caps residency at 2 blocks/CU = 4 waves/EU. Pin the register
// allocator to exactly that occupancy: 128-VGPR budget, no spills. R4's
// __launch_bounds__(512,4) let the allocator chase 8 waves/EU -> 64 VGPR ->
// scratch spill of acc/q-frags inside the kt loop (stall-bound at 573us).
__global__ __launch_bounds__(THREADS)
__attribute__((amdgpu_waves_per_eu(4, 4)))
void pm_attn(
    const float* __restrict__ Qg, const float* __restrict__ Kg,
    const float* __restrict__ Vg, const float* __restrict__ isf,
    float* __restrict__ Og)
{
  __shared__ __align__(16) short smem[SMEM_SHORTS];
  short* const Khi = smem;
  short* const Klo = smem + 8704;
  short* const Vt  = smem + 17408;
  short* const Pt  = smem + 26624;
  unsigned short* const Ms = (unsigned short*)(smem + 35840);

  const int tid  = threadIdx.x;
  const int lane = tid & 63;
  const int wid  = tid >> 6;       // wave 0..7, owns q rows [wid*16, wid*16+16)
  const int lg   = lane >> 4;      // 0..3
  const int tx   = lane & 15;

  // XCD-aware swizzle: 16 heads per XCD, all 8 q-blocks of a head colocated
  const int swz   = (blockIdx.x & 7) * 128 + (blockIdx.x >> 3);
  const int head  = swz >> 3;
  const int qbase = (swz & 7) * TQ;

  const size_t hoff = (size_t)head * (SS * DD);
  const float* Qh = Qg + hoff + (size_t)qbase * DD;
  const float* Kh = Kg + hoff;
  const float* Vh = Vg + hoff;
  float*       Oh = Og + hoff + (size_t)qbase * DD;

  // ---- Q fragments straight from global (row = wid*16+tx, no LDS) ----
  const int qrow = wid * 16 + tx;
  bf16x8 qhi[4], qlo[4];
#pragma unroll
  for (int ds = 0; ds < 4; ++ds) {
    const float* qp = Qh + qrow * DD + ds * 32 + lg * 8;
    float x[8];
    *(float4*)&x[0] = *(const float4*)qp;
    *(float4*)&x[4] = *(const float4*)(qp + 4);
#pragma unroll
    for (int e = 0; e < 8; ++e) {
      short h, l;
      split2(x[e], h, l);
      qhi[ds][e] = h;
      qlo[ds][e] = l;
    }
  }

  f32x4 acc[8];
#pragma unroll
  for (int n = 0; n < 8; ++n) acc[n] = (f32x4){0.f, 0.f, 0.f, 0.f};
  float mrun = -1e30f, lrun = 0.f;

  // ---- dropout half-word ownership: thread t -> row t>>2, k-base (t&3)*16 ----
  const uint32_t ctrbase = ((uint32_t)head << 20) |
                           ((uint32_t)(qbase + (tid >> 2)) << 10) |
                           (uint32_t)((tid & 3) * 16);
  // prologue: tiles 0 and 1
  Ms[tid]       = (unsigned short)maskhalf(ctrbase);
  Ms[512 + tid] = (unsigned short)maskhalf(ctrbase + 64u);

  const int vd = tid & 127;        // V-stage: this thread's d row
  const int vq = tid >> 7;         // and 16-k quarter

  for (int kt = 0; kt < NKT; ++kt) {
    const float* Kt  = Kh + (size_t)kt * (TK * DD);
    const float* Vtg = Vh + (size_t)kt * (TK * DD);

    __syncthreads();   // (a): prev PV done reading LDS

    // ---- stage K tile: fp32 * (log2e/isf[k]) -> hi/lo bf16 ----
#pragma unroll
    for (int i = 0; i < 4; ++i) {
      int f = tid * 4 + i * 2048;
      int row = f >> 7, col = f & 127;
      float rsk = LOG2E * __builtin_amdgcn_rcpf(isf[kt * 64 + row]);
      float4 k4 = *(const float4*)(Kt + f);
      short h0, h1, h2, h3, l0, l1, l2, l3;
      split2(k4.x * rsk, h0, l0); split2(k4.y * rsk, h1, l1);
      split2(k4.z * rsk, h2, l2); split2(k4.w * rsk, h3, l3);
      uint2 ph = { pack2(h0, h1), pack2(h2, h3) };
      uint2 pl = { pack2(l0, l1), pack2(l2, l3) };
      *(uint2*)&Khi[row * 136 + col] = ph;
      *(uint2*)&Klo[row * 136 + col] = pl;
    }
    // ---- stage V tile transposed: Vt[d][k] = V[k][d], natural k order ----
#pragma unroll
    for (int j4 = 0; j4 < 4; ++j4) {
      int k0 = vq * 16 + j4 * 4;
      float a0 = Vtg[(k0 + 0) * DD + vd];
      float a1 = Vtg[(k0 + 1) * DD + vd];
      float a2 = Vtg[(k0 + 2) * DD + vd];
      float a3 = Vtg[(k0 + 3) * DD + vd];
      uint2 wv = { pack2(f2bf(a0), f2bf(a1)), pack2(f2bf(a2), f2bf(a3)) };
      *(uint2*)&Vt[vd * 72 + k0] = wv;
    }
    __syncthreads();   // (b): K/V visible

    // ---- swapped QK^T: D[k][q] = K·Q^T; lane owns q=tx, k = kj*16+lg*4+r ----
    f32x4 sc[4];
#pragma unroll
    for (int kj = 0; kj < 4; ++kj) sc[kj] = (f32x4){0.f, 0.f, 0.f, 0.f};
#pragma unroll
    for (int ds = 0; ds < 4; ++ds) {
#pragma unroll
      for (int kj = 0; kj < 4; ++kj) {
        int off = (kj * 16 + tx) * 136 + ds * 32 + lg * 8;
        bf16x8 bhi = *(const bf16x8*)&Khi[off];
        bf16x8 blo = *(const bf16x8*)&Klo[off];
        sc[kj] = MFMA16(bhi, qhi[ds], sc[kj]);
        sc[kj] = MFMA16(bhi, qlo[ds], sc[kj]);
        sc[kj] = MFMA16(blo, qhi[ds], sc[kj]);
      }
    }

    // ---- online softmax (log2 domain), defer-max ----
    float pmax = sc[0][0];
#pragma unroll
    for (int kj = 0; kj < 4; ++kj)
#pragma unroll
      for (int r = 0; r < 4; ++r) pmax = fmaxf(pmax, sc[kj][r]);

    if (!__all(pmax <= mrun + DEFER_THR)) {
      float mt = fmaxf(pmax, __shfl_xor(pmax, 16, 64));
      mt = fmaxf(mt, __shfl_xor(mt, 32, 64));
      float mnew = fmaxf(mrun, mt);
      float corr = exp2f(mrun - mnew);
      lrun *= corr;
#pragma unroll
      for (int r = 0; r < 4; ++r) {
        float cr = __shfl(corr, (lane & 48) | (lg * 4 + r), 64);
#pragma unroll
        for (int n = 0; n < 8; ++n) acc[n][r] *= cr;
      }
      mrun = mnew;
    }

    // mask words for this lane's q row
    uint2 ww = *(const uint2*)&Ms[(kt & 1) * 512 + (wid * 16 + tx) * 4];
    float rsum = 0.f;
#pragma unroll
    for (int kj = 0; kj < 4; ++kj) {
      uint32_t w = (kj < 2) ? ww.x : ww.y;
      int bb = (kj & 1) * 16 + lg * 4;
      float p0 = exp2f(sc[kj][0] - mrun);
      float p1 = exp2f(sc[kj][1] - mrun);
      float p2 = exp2f(sc[kj][2] - mrun);
      float p3 = exp2f(sc[kj][3] - mrun);
      rsum += (p0 + p1) + (p2 + p3);
      short b0 = ((w >> (bb + 0)) & 1u) ? f2bf(p0) : (short)0;
      short b1 = ((w >> (bb + 1)) & 1u) ? f2bf(p1) : (short)0;
      short b2 = ((w >> (bb + 2)) & 1u) ? f2bf(p2) : (short)0;
      short b3 = ((w >> (bb + 3)) & 1u) ? f2bf(p3) : (short)0;
      uint2 pw = { pack2(b0, b1), pack2(b2, b3) };
      *(uint2*)&Pt[(wid * 16 + tx) * 72 + kj * 16 + lg * 4] = pw;
    }
    rsum += __shfl_xor(rsum, 16, 64);
    rsum += __shfl_xor(rsum, 32, 64);
    lrun += rsum;

    // ---- pipelined threefry for tile kt+2 (overlaps with PV/MFMA) ----
    uint32_t nexth = 0;
    if (kt + 2 < NKT) nexth = maskhalf(ctrbase + (uint32_t)((kt + 2) * 64));

    __syncthreads();   // (c): P ready; Ms[kt&1] readers done

    if (kt + 2 < NKT) Ms[(kt & 1) * 512 + tid] = (unsigned short)nexth;

    // ---- PV: acc[q][d] += P[q][k] * V[k][d] ----
#pragma unroll
    for (int ks = 0; ks < 2; ++ks) {
      bf16x8 pa = *(const bf16x8*)&Pt[(wid * 16 + tx) * 72 + ks * 32 + lg * 8];
#pragma unroll
      for (int n = 0; n < 8; ++n) {
        bf16x8 vb = *(const bf16x8*)&Vt[(n * 16 + tx) * 72 + ks * 32 + lg * 8];
        acc[n] = MFMA16(pa, vb, acc[n]);
      }
    }
  }

  // ---- epilogue: out = acc / (0.9 * l) ----
#pragma unroll
  for (int r = 0; r < 4; ++r) {
    float lr = __shfl(lrun, (lane & 48) | (lg * 4 + r), 64);
    float inv = 1.0f / (0.9f * lr);
    int orow = wid * 16 + lg * 4 + r;
#pragma unroll
    for (int n = 0; n < 8; ++n)
      Oh[orow * DD + n * 16 + tx] = acc[n][r] * inv;
  }
}

extern "C" void kernel_launch(void* const* d_in, const int* in_sizes, int n_in,
                              void* d_out, int out_size, void* d_ws, size_t ws_size,
                              hipStream_t stream) {
  const float* q   = (const float*)d_in[0];
  const float* k   = (const float*)d_in[1];
  const float* v   = (const float*)d_in[2];
  const float* isf = (const float*)d_in[3];

  pm_attn<<<dim3(NHEAD * (SS / TQ)), dim3(THREADS), 0, stream>>>(
      q, k, v, isf, (float*)d_out);
}

// Round 6
// 462.030 us; speedup vs baseline: 1.0673x; 1.0673x over previous
//
#include <hip/hip_runtime.h>
#include <hip/hip_bf16.h>
#include <stdint.h>

#define SS 1024
#define DD 128
#define TQ 128          // q rows per block
#define TK 64           // kv cols per tile
#define NKT (SS/TK)     // 16
#define THREADS 512     // 8 waves
#define NHEAD 128
#define LOG2E 1.44269504088896340736f
#define DEFER_THR 11.5415603f   // 8 * log2e

// prep tile (shorts): Khi[64][128] swz | Klo[64][128] swz | Vt[128][64] swz
#define TILE_SHORTS 24576
#define PREP_BYTES ((size_t)NHEAD * NKT * TILE_SHORTS * 2)   // 96 MiB

typedef short bf16x8 __attribute__((ext_vector_type(8)));
typedef float f32x4  __attribute__((ext_vector_type(4)));

// ---------------- threefry2x32, key = (0, 42) — bit-exact (R1) -------------
__device__ __forceinline__ uint32_t rotl32(uint32_t v, uint32_t s) {
  // rotl(v,s) = alignbit(v, v, 32-s)  (funnel shift right by 32-s)
  return __builtin_amdgcn_alignbit(v, v, 32u - s);
}
__device__ __forceinline__ uint32_t threefry_bits(uint32_t ctr) {
  const uint32_t K0 = 0u, K1 = 42u;
  const uint32_t K2 = K0 ^ K1 ^ 0x1BD11BDAu;
  uint32_t x0 = K0;
  uint32_t x1 = ctr + K1;
#define TF_RND(r) { x0 += x1; x1 = rotl32(x1, r); x1 ^= x0; }
  TF_RND(13u) TF_RND(15u) TF_RND(26u) TF_RND(6u)
  x0 += K1; x1 += K2 + 1u;
  TF_RND(17u) TF_RND(29u) TF_RND(16u) TF_RND(24u)
  x0 += K2; x1 += K0 + 2u;
  TF_RND(13u) TF_RND(15u) TF_RND(26u) TF_RND(6u)
  x0 += K0; x1 += K1 + 3u;
  TF_RND(17u) TF_RND(29u) TF_RND(16u) TF_RND(24u)
  x0 += K1; x1 += K2 + 4u;
  TF_RND(13u) TF_RND(15u) TF_RND(26u) TF_RND(6u)
  x0 += K2; x1 += K0 + 5u;
#undef TF_RND
  return x0 ^ x1;
}
// 16 keep-bits starting at element counter `base` (bit b: uniform < 0.9f)
__device__ __forceinline__ uint32_t maskhalf(uint32_t base) {
  uint32_t h = 0u;
#pragma unroll 4
  for (int b = 0; b < 16; ++b)
    h |= (threefry_bits(base + (uint32_t)b) < 0xE6666600u) ? (1u << b) : 0u;
  return h;
}

// ---------------- bf16 helpers --------------------------------------------
__device__ __forceinline__ short f2bf(float x) {
  return __builtin_bit_cast(short, __float2bfloat16(x));   // RNE
}
__device__ __forceinline__ float bf2f(short b) {
  return __uint_as_float(((uint32_t)(uint16_t)b) << 16);
}
__device__ __forceinline__ uint32_t pack2(short a, short b) {
  return (uint32_t)(uint16_t)a | ((uint32_t)(uint16_t)b << 16);
}
__device__ __forceinline__ void split2(float x, short& hi, short& lo) {
  hi = f2bf(x);
  lo = f2bf(x - bf2f(hi));
}

#define MFMA16(A, B, C) __builtin_amdgcn_mfma_f32_16x16x32_bf16(A, B, C, 0, 0, 0)

// async global->LDS, 16B per lane (dest = wave-uniform base + lane*16)
__device__ __forceinline__ void gl_lds16(const void* g, void* lds) {
  auto gp = (const __attribute__((address_space(1))) uint32_t*)(uintptr_t)g;
  auto lp = (__attribute__((address_space(3))) uint32_t*)(uintptr_t)lds;
  __builtin_amdgcn_global_load_lds(gp, lp, 16, 0, 0);
}

// ============================================================================
// prepass: per (head, kt) build the 48KB LDS image:
//   Khi[k][d] (row-scaled by log2e/isf, hi bf16), chunk-swizzle c^=(k&15)
//   Klo same, lo bf16
//   Vt[d][kk] bf16 transposed, chunk-swizzle c^=(d&7)
// ============================================================================
__global__ __launch_bounds__(256) void pm_prep(
    const float* __restrict__ Kg, const float* __restrict__ Vg,
    const float* __restrict__ isf, short* __restrict__ prep)
{
  __shared__ short lv[64 * 132];
  const int bid = blockIdx.x;          // head*16 + kt
  const int head = bid >> 4, kt = bid & 15;
  const int tid = threadIdx.x;
  const float* Kt  = Kg + ((size_t)head * SS + (size_t)kt * TK) * DD;
  const float* Vtg = Vg + ((size_t)head * SS + (size_t)kt * TK) * DD;
  short* tile = prep + (size_t)bid * TILE_SHORTS;

#pragma unroll
  for (int i = 0; i < 8; ++i) {
    int f = tid * 4 + i * 1024;        // 8192 fp32 elements
    int k = f >> 7, d = f & 127;
    float rsk = LOG2E * __builtin_amdgcn_rcpf(isf[kt * TK + k]);
    float4 k4 = *(const float4*)(Kt + f);
    short h0, h1, h2, h3, l0, l1, l2, l3;
    split2(k4.x * rsk, h0, l0); split2(k4.y * rsk, h1, l1);
    split2(k4.z * rsk, h2, l2); split2(k4.w * rsk, h3, l3);
    int idx = k * 128 + (d & 7) + 8 * ((d >> 3) ^ (k & 15));
    *(uint2*)&tile[idx]        = (uint2){pack2(h0, h1), pack2(h2, h3)};
    *(uint2*)&tile[8192 + idx] = (uint2){pack2(l0, l1), pack2(l2, l3)};
    // stage V bf16 [k][d] for transpose
    float4 v4 = *(const float4*)(Vtg + f);
    *(uint2*)&lv[k * 132 + d] = (uint2){pack2(f2bf(v4.x), f2bf(v4.y)),
                                        pack2(f2bf(v4.z), f2bf(v4.w))};
  }
  __syncthreads();
  // transposed, swizzled V: slot s of row d holds kk-chunk (s ^ (d&7))
#pragma unroll
  for (int j = 0; j < 4; ++j) {
    int c = tid * 4 + j;               // 1024 chunks of 8 shorts
    int d = c >> 3, s = c & 7;
    int kk0 = (s ^ (d & 7)) * 8;
    short tmp[8];
#pragma unroll
    for (int e = 0; e < 8; ++e) tmp[e] = lv[(kk0 + e) * 132 + d];
    *(uint4*)&tile[16384 + d * 64 + s * 8] = *(uint4*)tmp;
  }
}

// ============================================================================
// main fused kernel (prepass path): zero-VALU staging via global_load_lds
// LDS (shorts): Khi @0 (8192), Klo @8192, Vt @16384 (8192),
//               Pt[128][72] @24576, Ms ushort[2][512] @33792  -> 34816 sh
// ============================================================================
__global__ __launch_bounds__(THREADS) void pm_attn(
    const float* __restrict__ Qg, const short* __restrict__ prep,
    float* __restrict__ Og)
{
  __shared__ __align__(16) short smem[34816];
  short* const Khs = smem;
  short* const Kls = smem + 8192;
  short* const Vts = smem + 16384;
  short* const Pt  = smem + 24576;
  unsigned short* const Ms = (unsigned short*)(smem + 33792);

  const int tid  = threadIdx.x;
  const int lane = tid & 63;
  const int wid  = tid >> 6;       // wave 0..7, owns q rows [wid*16, +16)
  const int lg   = lane >> 4;      // 0..3
  const int tx   = lane & 15;

  // XCD-aware swizzle: 16 heads per XCD, all 8 q-blocks of a head colocated
  const int swz   = (blockIdx.x & 7) * 128 + (blockIdx.x >> 3);
  const int head  = swz >> 3;
  const int qbase = (swz & 7) * TQ;

  const size_t hoff = (size_t)head * (SS * DD);
  const float* Qh = Qg + hoff + (size_t)qbase * DD;
  float*       Oh = Og + hoff + (size_t)qbase * DD;

  // ---- Q fragments straight from global (row = wid*16+tx) ----
  const int qrow = wid * 16 + tx;
  bf16x8 qhi[4], qlo[4];
#pragma unroll
  for (int ds = 0; ds < 4; ++ds) {
    const float* qp = Qh + qrow * DD + ds * 32 + lg * 8;
    float x[8];
    *(float4*)&x[0] = *(const float4*)qp;
    *(float4*)&x[4] = *(const float4*)(qp + 4);
#pragma unroll
    for (int e = 0; e < 8; ++e) {
      short h, l;
      split2(x[e], h, l);
      qhi[ds][e] = h;
      qlo[ds][e] = l;
    }
  }

  f32x4 acc[8];
#pragma unroll
  for (int n = 0; n < 8; ++n) acc[n] = (f32x4){0.f, 0.f, 0.f, 0.f};
  float mrun = -1e30f, lrun = 0.f;

  // dropout half-word ownership: thread t -> q row t>>2, k-base (t&3)*16
  const uint32_t ctrbase = ((uint32_t)head << 20) |
                           ((uint32_t)(qbase + (tid >> 2)) << 10) |
                           (uint32_t)((tid & 3) * 16);
  Ms[tid]       = (unsigned short)maskhalf(ctrbase);
  Ms[512 + tid] = (unsigned short)maskhalf(ctrbase + 64u);

  const int vswz = tx & 7;   // V row-swizzle key (d&7 == tx&7 for d=n*16+tx)

  for (int kt = 0; kt < NKT; ++kt) {
    __syncthreads();   // (a): prev PV done reading K/V LDS

    // ---- issue async 48KB tile DMA (zero VALU); drained at barrier (b) ----
    {
      const char* gw = (const char*)(prep + (size_t)(head * NKT + kt) * TILE_SHORTS)
                       + wid * 1024 + lane * 16;
      char* lw = (char*)smem + wid * 1024;
#pragma unroll
      for (int i = 0; i < 6; ++i)
        gl_lds16(gw + i * 8192, lw + i * 8192);
    }

    // ---- threefry for tile kt+2 — hides the DMA latency ----
    uint32_t nexth = 0;
    if (kt + 2 < NKT) nexth = maskhalf(ctrbase + (uint32_t)((kt + 2) * 64));

    __syncthreads();   // (b): K/V visible (compiler drains vmcnt here)

    // ---- swapped QK^T (pre-scaled, log2 domain): lane owns q=tx ----
    f32x4 sc[4];
#pragma unroll
    for (int kj = 0; kj < 4; ++kj) sc[kj] = (f32x4){0.f, 0.f, 0.f, 0.f};
#pragma unroll
    for (int ds = 0; ds < 4; ++ds) {
#pragma unroll
      for (int kj = 0; kj < 4; ++kj) {
        int off = (kj * 16 + tx) * 128 + 8 * ((ds * 4 + lg) ^ tx);
        bf16x8 bhi = *(const bf16x8*)&Khs[off];
        bf16x8 blo = *(const bf16x8*)&Kls[off];
        sc[kj] = MFMA16(bhi, qhi[ds], sc[kj]);
        sc[kj] = MFMA16(bhi, qlo[ds], sc[kj]);
        sc[kj] = MFMA16(blo, qhi[ds], sc[kj]);
      }
    }

    // ---- online softmax (log2 domain), defer-max ----
    float pmax = sc[0][0];
#pragma unroll
    for (int kj = 0; kj < 4; ++kj)
#pragma unroll
      for (int r = 0; r < 4; ++r) pmax = fmaxf(pmax, sc[kj][r]);

    if (!__all(pmax <= mrun + DEFER_THR)) {
      float mt = fmaxf(pmax, __shfl_xor(pmax, 16, 64));
      mt = fmaxf(mt, __shfl_xor(mt, 32, 64));
      float mnew = fmaxf(mrun, mt);
      float corr = exp2f(mrun - mnew);
      lrun *= corr;
#pragma unroll
      for (int r = 0; r < 4; ++r) {
        float cr = __shfl(corr, (lane & 48) | (lg * 4 + r), 64);
#pragma unroll
        for (int n = 0; n < 8; ++n) acc[n][r] *= cr;
      }
      mrun = mnew;
    }

    // ---- exp2, dropout, packed P write ----
    uint2 ww = *(const uint2*)&Ms[(kt & 1) * 512 + (wid * 16 + tx) * 4];
    float rsum = 0.f;
#pragma unroll
    for (int kj = 0; kj < 4; ++kj) {
      uint32_t w = (kj < 2) ? ww.x : ww.y;
      int bb = (kj & 1) * 16 + lg * 4;
      float p0 = exp2f(sc[kj][0] - mrun);
      float p1 = exp2f(sc[kj][1] - mrun);
      float p2 = exp2f(sc[kj][2] - mrun);
      float p3 = exp2f(sc[kj][3] - mrun);
      rsum += (p0 + p1) + (p2 + p3);
      short b0 = ((w >> (bb + 0)) & 1u) ? f2bf(p0) : (short)0;
      short b1 = ((w >> (bb + 1)) & 1u) ? f2bf(p1) : (short)0;
      short b2 = ((w >> (bb + 2)) & 1u) ? f2bf(p2) : (short)0;
      short b3 = ((w >> (bb + 3)) & 1u) ? f2bf(p3) : (short)0;
      uint2 pw = { pack2(b0, b1), pack2(b2, b3) };
      *(uint2*)&Pt[(wid * 16 + tx) * 72 + kj * 16 + lg * 4] = pw;
    }
    rsum += __shfl_xor(rsum, 16, 64);
    rsum += __shfl_xor(rsum, 32, 64);
    lrun += rsum;

    __syncthreads();   // (c): P ready; Ms[kt&1] readers done

    if (kt + 2 < NKT) Ms[(kt & 1) * 512 + tid] = (unsigned short)nexth;

    // ---- PV: acc[q][d] += P[q][k] * Vt[d][k] (swizzled V reads) ----
#pragma unroll
    for (int ks = 0; ks < 2; ++ks) {
      bf16x8 pa = *(const bf16x8*)&Pt[(wid * 16 + tx) * 72 + ks * 32 + lg * 8];
#pragma unroll
      for (int n = 0; n < 8; ++n) {
        int dr = n * 16 + tx;
        bf16x8 vb = *(const bf16x8*)&Vts[dr * 64 + 8 * ((ks * 4 + lg) ^ vswz)];
        acc[n] = MFMA16(pa, vb, acc[n]);
      }
    }
  }

  // ---- epilogue: out = acc / (0.9 * l) ----
#pragma unroll
  for (int r = 0; r < 4; ++r) {
    float lr = __shfl(lrun, (lane & 48) | (lg * 4 + r), 64);
    float inv = 1.0f / (0.9f * lr);
    int orow = wid * 16 + lg * 4 + r;
#pragma unroll
    for (int n = 0; n < 8; ++n)
      Oh[orow * DD + n * 16 + tx] = acc[n][r] * inv;
  }
}

// ============================================================================
// fallback (ws too small): R5 monolithic kernel, in-kernel staging
// ============================================================================
#define SMEM_SHORTS_FB 36864
__global__ __launch_bounds__(THREADS) void pm_attn_fb(
    const float* __restrict__ Qg, const float* __restrict__ Kg,
    const float* __restrict__ Vg, const float* __restrict__ isf,
    float* __restrict__ Og)
{
  __shared__ __align__(16) short smem[SMEM_SHORTS_FB];
  short* const Khi = smem;
  short* const Klo = smem + 8704;
  short* const Vt  = smem + 17408;
  short* const Pt  = smem + 26624;
  unsigned short* const Ms = (unsigned short*)(smem + 35840);

  const int tid  = threadIdx.x;
  const int lane = tid & 63;
  const int wid  = tid >> 6;
  const int lg   = lane >> 4;
  const int tx   = lane & 15;

  const int swz   = (blockIdx.x & 7) * 128 + (blockIdx.x >> 3);
  const int head  = swz >> 3;
  const int qbase = (swz & 7) * TQ;

  const size_t hoff = (size_t)head * (SS * DD);
  const float* Qh = Qg + hoff + (size_t)qbase * DD;
  const float* Kh = Kg + hoff;
  const float* Vh = Vg + hoff;
  float*       Oh = Og + hoff + (size_t)qbase * DD;

  const int qrow = wid * 16 + tx;
  bf16x8 qhi[4], qlo[4];
#pragma unroll
  for (int ds = 0; ds < 4; ++ds) {
    const float* qp = Qh + qrow * DD + ds * 32 + lg * 8;
    float x[8];
    *(float4*)&x[0] = *(const float4*)qp;
    *(float4*)&x[4] = *(const float4*)(qp + 4);
#pragma unroll
    for (int e = 0; e < 8; ++e) {
      short h, l;
      split2(x[e], h, l);
      qhi[ds][e] = h;
      qlo[ds][e] = l;
    }
  }

  f32x4 acc[8];
#pragma unroll
  for (int n = 0; n < 8; ++n) acc[n] = (f32x4){0.f, 0.f, 0.f, 0.f};
  float mrun = -1e30f, lrun = 0.f;

  const uint32_t ctrbase = ((uint32_t)head << 20) |
                           ((uint32_t)(qbase + (tid >> 2)) << 10) |
                           (uint32_t)((tid & 3) * 16);
  Ms[tid]       = (unsigned short)maskhalf(ctrbase);
  Ms[512 + tid] = (unsigned short)maskhalf(ctrbase + 64u);

  const int vd = tid & 127;
  const int vq = tid >> 7;

  for (int kt = 0; kt < NKT; ++kt) {
    const float* Kt  = Kh + (size_t)kt * (TK * DD);
    const float* Vtg = Vh + (size_t)kt * (TK * DD);

    __syncthreads();
#pragma unroll
    for (int i = 0; i < 4; ++i) {
      int f = tid * 4 + i * 2048;
      int row = f >> 7, col = f & 127;
      float rsk = LOG2E * __builtin_amdgcn_rcpf(isf[kt * 64 + row]);
      float4 k4 = *(const float4*)(Kt + f);
      short h0, h1, h2, h3, l0, l1, l2, l3;
      split2(k4.x * rsk, h0, l0); split2(k4.y * rsk, h1, l1);
      split2(k4.z * rsk, h2, l2); split2(k4.w * rsk, h3, l3);
      *(uint2*)&Khi[row * 136 + col] = (uint2){pack2(h0, h1), pack2(h2, h3)};
      *(uint2*)&Klo[row * 136 + col] = (uint2){pack2(l0, l1), pack2(l2, l3)};
    }
#pragma unroll
    for (int j4 = 0; j4 < 4; ++j4) {
      int k0 = vq * 16 + j4 * 4;
      float a0 = Vtg[(k0 + 0) * DD + vd];
      float a1 = Vtg[(k0 + 1) * DD + vd];
      float a2 = Vtg[(k0 + 2) * DD + vd];
      float a3 = Vtg[(k0 + 3) * DD + vd];
      *(uint2*)&Vt[vd * 72 + k0] =
          (uint2){pack2(f2bf(a0), f2bf(a1)), pack2(f2bf(a2), f2bf(a3))};
    }
    __syncthreads();

    f32x4 sc[4];
#pragma unroll
    for (int kj = 0; kj < 4; ++kj) sc[kj] = (f32x4){0.f, 0.f, 0.f, 0.f};
#pragma unroll
    for (int ds = 0; ds < 4; ++ds) {
#pragma unroll
      for (int kj = 0; kj < 4; ++kj) {
        int off = (kj * 16 + tx) * 136 + ds * 32 + lg * 8;
        bf16x8 bhi = *(const bf16x8*)&Khi[off];
        bf16x8 blo = *(const bf16x8*)&Klo[off];
        sc[kj] = MFMA16(bhi, qhi[ds], sc[kj]);
        sc[kj] = MFMA16(bhi, qlo[ds], sc[kj]);
        sc[kj] = MFMA16(blo, qhi[ds], sc[kj]);
      }
    }

    float pmax = sc[0][0];
#pragma unroll
    for (int kj = 0; kj < 4; ++kj)
#pragma unroll
      for (int r = 0; r < 4; ++r) pmax = fmaxf(pmax, sc[kj][r]);

    if (!__all(pmax <= mrun + DEFER_THR)) {
      float mt = fmaxf(pmax, __shfl_xor(pmax, 16, 64));
      mt = fmaxf(mt, __shfl_xor(mt, 32, 64));
      float mnew = fmaxf(mrun, mt);
      float corr = exp2f(mrun - mnew);
      lrun *= corr;
#pragma unroll
      for (int r = 0; r < 4; ++r) {
        float cr = __shfl(corr, (lane & 48) | (lg * 4 + r), 64);
#pragma unroll
        for (int n = 0; n < 8; ++n) acc[n][r] *= cr;
      }
      mrun = mnew;
    }

    uint2 ww = *(const uint2*)&Ms[(kt & 1) * 512 + (wid * 16 + tx) * 4];
    float rsum = 0.f;
#pragma unroll
    for (int kj = 0; kj < 4; ++kj) {
      uint32_t w = (kj < 2) ? ww.x : ww.y;
      int bb = (kj & 1) * 16 + lg * 4;
      float p0 = exp2f(sc[kj][0] - mrun);
      float p1 = exp2f(sc[kj][1] - mrun);
      float p2 = exp2f(sc[kj][2] - mrun);
      float p3 = exp2f(sc[kj][3] - mrun);
      rsum += (p0 + p1) + (p2 + p3);
      short b0 = ((w >> (bb + 0)) & 1u) ? f2bf(p0) : (short)0;
      short b1 = ((w >> (bb + 1)) & 1u) ? f2bf(p1) : (short)0;
      short b2 = ((w >> (bb + 2)) & 1u) ? f2bf(p2) : (short)0;
      short b3 = ((w >> (bb + 3)) & 1u) ? f2bf(p3) : (short)0;
      *(uint2*)&Pt[(wid * 16 + tx) * 72 + kj * 16 + lg * 4] =
          (uint2){pack2(b0, b1), pack2(b2, b3)};
    }
    rsum += __shfl_xor(rsum, 16, 64);
    rsum += __shfl_xor(rsum, 32, 64);
    lrun += rsum;

    uint32_t nexth = 0;
    if (kt + 2 < NKT) nexth = maskhalf(ctrbase + (uint32_t)((kt + 2) * 64));

    __syncthreads();

    if (kt + 2 < NKT) Ms[(kt & 1) * 512 + tid] = (unsigned short)nexth;

#pragma unroll
    for (int ks = 0; ks < 2; ++ks) {
      bf16x8 pa = *(const bf16x8*)&Pt[(wid * 16 + tx) * 72 + ks * 32 + lg * 8];
#pragma unroll
      for (int n = 0; n < 8; ++n) {
        bf16x8 vb = *(const bf16x8*)&Vt[(n * 16 + tx) * 72 + ks * 32 + lg * 8];
        acc[n] = MFMA16(pa, vb, acc[n]);
      }
    }
  }

#pragma unroll
  for (int r = 0; r < 4; ++r) {
    float lr = __shfl(lrun, (lane & 48) | (lg * 4 + r), 64);
    float inv = 1.0f / (0.9f * lr);
    int orow = wid * 16 + lg * 4 + r;
#pragma unroll
    for (int n = 0; n < 8; ++n)
      Oh[orow * DD + n * 16 + tx] = acc[n][r] * inv;
  }
}

extern "C" void kernel_launch(void* const* d_in, const int* in_sizes, int n_in,
                              void* d_out, int out_size, void* d_ws, size_t ws_size,
                              hipStream_t stream) {
  const float* q   = (const float*)d_in[0];
  const float* k   = (const float*)d_in[1];
  const float* v   = (const float*)d_in[2];
  const float* isf = (const float*)d_in[3];

  if (ws_size >= PREP_BYTES) {
    pm_prep<<<dim3(NHEAD * NKT), dim3(256), 0, stream>>>(k, v, isf, (short*)d_ws);
    pm_attn<<<dim3(NHEAD * (SS / TQ)), dim3(THREADS), 0, stream>>>(
        q, (const short*)d_ws, (float*)d_out);
  } else {
    pm_attn_fb<<<dim3(NHEAD * (SS / TQ)), dim3(THREADS), 0, stream>>>(
        q, k, v, isf, (float*)d_out);
  }
}

// Round 7
// 365.729 us; speedup vs baseline: 1.3484x; 1.2633x over previous
//
#include <hip/hip_runtime.h>
#include <hip/hip_bf16.h>
#include <stdint.h>

#define SS 1024
#define DD 128
#define TQ 64           // q rows per block (4 waves x 16)
#define TK 64           // kv cols per tile
#define NKT (SS/TK)     // 16
#define THREADS 256     // 4 waves
#define NBLK (128 * (SS/TQ))   // 2048
#define NHEAD 128
#define LOG2E 1.44269504088896340736f
#define DEFER_THR 11.5415603f   // 8 * log2e

// prep tile (shorts): Kf[64][128] fp16 swz | Vt[128][64] fp16 swz
#define TILE_SHORTS 16384
#define PREP_BYTES ((size_t)NHEAD * NKT * TILE_SHORTS * 2)   // 64 MiB

typedef _Float16 f16x8 __attribute__((ext_vector_type(8)));
typedef _Float16 f16x4 __attribute__((ext_vector_type(4)));
typedef short bf16x8 __attribute__((ext_vector_type(8)));
typedef float f32x4  __attribute__((ext_vector_type(4)));

// ---------------- threefry2x32, key = (0, 42) — bit-exact (R1) -------------
__device__ __forceinline__ uint32_t rotl32(uint32_t v, uint32_t s) {
  return __builtin_amdgcn_alignbit(v, v, 32u - s);
}
__device__ __forceinline__ uint32_t threefry_bits(uint32_t ctr) {
  const uint32_t K0 = 0u, K1 = 42u;
  const uint32_t K2 = K0 ^ K1 ^ 0x1BD11BDAu;
  uint32_t x0 = K0;
  uint32_t x1 = ctr + K1;
#define TF_RND(r) { x0 += x1; x1 = rotl32(x1, r); x1 ^= x0; }
  TF_RND(13u) TF_RND(15u) TF_RND(26u) TF_RND(6u)
  x0 += K1; x1 += K2 + 1u;
  TF_RND(17u) TF_RND(29u) TF_RND(16u) TF_RND(24u)
  x0 += K2; x1 += K0 + 2u;
  TF_RND(13u) TF_RND(15u) TF_RND(26u) TF_RND(6u)
  x0 += K0; x1 += K1 + 3u;
  TF_RND(17u) TF_RND(29u) TF_RND(16u) TF_RND(24u)
  x0 += K1; x1 += K2 + 4u;
  TF_RND(13u) TF_RND(15u) TF_RND(26u) TF_RND(6u)
  x0 += K2; x1 += K0 + 5u;
#undef TF_RND
  return x0 ^ x1;
}
// 16 keep-bits starting at element counter `base` (bit b: uniform < 0.9f)
__device__ __forceinline__ uint32_t maskhalf(uint32_t base) {
  uint32_t h = 0u;
#pragma unroll 4
  for (int b = 0; b < 16; ++b)
    h |= (threefry_bits(base + (uint32_t)b) < 0xE6666600u) ? (1u << b) : 0u;
  return h;
}

// ---------------- helpers ---------------------------------------------------
__device__ __forceinline__ short f2bf(float x) {
  return __builtin_bit_cast(short, __float2bfloat16(x));
}
__device__ __forceinline__ float bf2f(short b) {
  return __uint_as_float(((uint32_t)(uint16_t)b) << 16);
}
__device__ __forceinline__ uint32_t pack2(short a, short b) {
  return (uint32_t)(uint16_t)a | ((uint32_t)(uint16_t)b << 16);
}
__device__ __forceinline__ void split2(float x, short& hi, short& lo) {
  hi = f2bf(x);
  lo = f2bf(x - bf2f(hi));
}

#define MFMA16F(A, B, C) __builtin_amdgcn_mfma_f32_16x16x32_f16(A, B, C, 0, 0, 0)
#define MFMA16B(A, B, C) __builtin_amdgcn_mfma_f32_16x16x32_bf16(A, B, C, 0, 0, 0)

// async global->LDS, 16B per lane (dest = wave-uniform base + lane*16)
__device__ __forceinline__ void gl_lds16(const void* g, void* lds) {
  auto gp = (const __attribute__((address_space(1))) uint32_t*)(uintptr_t)g;
  auto lp = (__attribute__((address_space(3))) uint32_t*)(uintptr_t)lds;
  __builtin_amdgcn_global_load_lds(gp, lp, 16, 0, 0);
}

// ============================================================================
// prepass: per (head, kt) build the 32KB LDS image (fp16):
//   Kf[k][d]  scaled by log2e/isf[k], chunk-swizzle (d>>3)^(k&15)
//   Vt[d][kk] transposed,             chunk-swizzle slot^(d&7)
// ============================================================================
__global__ __launch_bounds__(256) void pm_prep(
    const float* __restrict__ Kg, const float* __restrict__ Vg,
    const float* __restrict__ isf, short* __restrict__ prep)
{
  __shared__ short lv[64 * 132];
  const int bid = blockIdx.x;          // head*16 + kt
  const int head = bid >> 4, kt = bid & 15;
  const int tid = threadIdx.x;
  const float* Kt  = Kg + ((size_t)head * SS + (size_t)kt * TK) * DD;
  const float* Vtg = Vg + ((size_t)head * SS + (size_t)kt * TK) * DD;
  short* tile = prep + (size_t)bid * TILE_SHORTS;

#pragma unroll
  for (int i = 0; i < 8; ++i) {
    int f = tid * 4 + i * 1024;        // 8192 fp32 elements
    int k = f >> 7, d = f & 127;
    float rsk = LOG2E * __builtin_amdgcn_rcpf(isf[kt * TK + k]);
    float4 k4 = *(const float4*)(Kt + f);
    f16x4 kh = { (_Float16)(k4.x * rsk), (_Float16)(k4.y * rsk),
                 (_Float16)(k4.z * rsk), (_Float16)(k4.w * rsk) };
    int idx = k * 128 + (d & 7) + 8 * ((d >> 3) ^ (k & 15));
    *(f16x4*)&tile[idx] = kh;
    // stage V fp16 [k][d] for transpose
    float4 v4 = *(const float4*)(Vtg + f);
    f16x4 vh = { (_Float16)v4.x, (_Float16)v4.y, (_Float16)v4.z, (_Float16)v4.w };
    *(f16x4*)&lv[k * 132 + d] = vh;
  }
  __syncthreads();
  // transposed, swizzled V: slot s of row d holds kk-chunk (s ^ (d&7))
#pragma unroll
  for (int j = 0; j < 4; ++j) {
    int c = tid * 4 + j;               // 1024 chunks of 8 shorts
    int d = c >> 3, s = c & 7;
    int kk0 = (s ^ (d & 7)) * 8;
    short tmp[8];
#pragma unroll
    for (int e = 0; e < 8; ++e) tmp[e] = lv[(kk0 + e) * 132 + d];
    *(uint4*)&tile[8192 + d * 64 + s * 8] = *(uint4*)tmp;
  }
}

// ============================================================================
// main fused kernel: fp16 single-term QK, 256 threads, TQ=64, 42KB LDS
// LDS (shorts): Kf @0 (8192), Vt @8192 (8192), Pt[64][72] @16384 (4608),
//               Ms u16[2][256] @20992  -> 21504 shorts = 42KB -> 3 blocks/CU
// ============================================================================
#define SMEM_SHORTS 21504

__global__ __launch_bounds__(THREADS) void pm_attn(
    const float* __restrict__ Qg, const short* __restrict__ prep,
    float* __restrict__ Og)
{
  __shared__ __align__(16) short smem[SMEM_SHORTS];
  short* const Kfs = smem;
  short* const Vts = smem + 8192;
  short* const Pt  = smem + 16384;
  unsigned short* const Ms = (unsigned short*)(smem + 20992);

  const int tid  = threadIdx.x;
  const int lane = tid & 63;
  const int wid  = tid >> 6;       // wave 0..3, owns q rows [wid*16, +16)
  const int lg   = lane >> 4;      // 0..3
  const int tx   = lane & 15;

  // XCD-aware swizzle: 2048 % 8 == 0, all 16 q-blocks of a head colocated
  const int swz   = (blockIdx.x & 7) * (NBLK / 8) + (blockIdx.x >> 3);
  const int head  = swz >> 4;
  const int qbase = (swz & 15) * TQ;

  const size_t hoff = (size_t)head * (SS * DD);
  const float* Qh = Qg + hoff + (size_t)qbase * DD;
  float*       Oh = Og + hoff + (size_t)qbase * DD;

  // ---- Q fragments straight from global (row = wid*16+tx), fp16 ----
  const int qrow = wid * 16 + tx;
  f16x8 qf[4];
#pragma unroll
  for (int ds = 0; ds < 4; ++ds) {
    const float* qp = Qh + qrow * DD + ds * 32 + lg * 8;
    float x[8];
    *(float4*)&x[0] = *(const float4*)qp;
    *(float4*)&x[4] = *(const float4*)(qp + 4);
#pragma unroll
    for (int e = 0; e < 8; ++e) qf[ds][e] = (_Float16)x[e];
  }

  f32x4 acc[8];
#pragma unroll
  for (int n = 0; n < 8; ++n) acc[n] = (f32x4){0.f, 0.f, 0.f, 0.f};
  float mrun = -1e30f, lrun = 0.f;

  // dropout ownership: thread t -> q row t>>2, k-quarter (t&3)*16
  const uint32_t ctrbase = ((uint32_t)head << 20) |
                           ((uint32_t)(qbase + (tid >> 2)) << 10) |
                           (uint32_t)((tid & 3) * 16);
  Ms[tid]       = (unsigned short)maskhalf(ctrbase);
  Ms[256 + tid] = (unsigned short)maskhalf(ctrbase + 64u);

  const int vswz = tx & 7;   // V row-swizzle key (d&7 == tx&7 for d=n*16+tx)

  for (int kt = 0; kt < NKT; ++kt) {
    __syncthreads();   // (a): prev PV done reading K/V LDS

    // ---- issue async 32KB tile DMA; drained at barrier (b) ----
    {
      const char* gw = (const char*)(prep + (size_t)(head * NKT + kt) * TILE_SHORTS)
                       + wid * 8192 + lane * 16;
      char* lw = (char*)smem + wid * 8192;
#pragma unroll
      for (int i = 0; i < 8; ++i)
        gl_lds16(gw + i * 1024, lw + i * 1024);
    }

    // ---- threefry for tile kt+2 — hides the DMA latency ----
    uint32_t nexth = 0;
    if (kt + 2 < NKT) nexth = maskhalf(ctrbase + (uint32_t)((kt + 2) * 64));

    __syncthreads();   // (b): K/V visible

    // ---- swapped QK^T (pre-scaled, log2 domain): lane owns q=tx ----
    f32x4 sc[4];
#pragma unroll
    for (int kj = 0; kj < 4; ++kj) sc[kj] = (f32x4){0.f, 0.f, 0.f, 0.f};
#pragma unroll
    for (int ds = 0; ds < 4; ++ds) {
#pragma unroll
      for (int kj = 0; kj < 4; ++kj) {
        int off = (kj * 16 + tx) * 128 + 8 * ((ds * 4 + lg) ^ tx);
        f16x8 kf = *(const f16x8*)&Kfs[off];
        sc[kj] = MFMA16F(kf, qf[ds], sc[kj]);
      }
    }

    // ---- online softmax (log2 domain), defer-max ----
    float pmax = sc[0][0];
#pragma unroll
    for (int kj = 0; kj < 4; ++kj)
#pragma unroll
      for (int r = 0; r < 4; ++r) pmax = fmaxf(pmax, sc[kj][r]);

    if (!__all(pmax <= mrun + DEFER_THR)) {
      float mt = fmaxf(pmax, __shfl_xor(pmax, 16, 64));
      mt = fmaxf(mt, __shfl_xor(mt, 32, 64));
      float mnew = fmaxf(mrun, mt);
      float corr = exp2f(mrun - mnew);
      lrun *= corr;
#pragma unroll
      for (int r = 0; r < 4; ++r) {
        float cr = __shfl(corr, (lane & 48) | (lg * 4 + r), 64);
#pragma unroll
        for (int n = 0; n < 8; ++n) acc[n][r] *= cr;
      }
      mrun = mnew;
    }

    // ---- exp2, dropout, packed fp16 P write ----
    uint2 ww = *(const uint2*)&Ms[(kt & 1) * 256 + (wid * 16 + tx) * 4];
    float rsum = 0.f;
#pragma unroll
    for (int kj = 0; kj < 4; ++kj) {
      uint32_t w = (kj < 2) ? ww.x : ww.y;
      int bb = (kj & 1) * 16 + lg * 4;
      float p0 = exp2f(sc[kj][0] - mrun);
      float p1 = exp2f(sc[kj][1] - mrun);
      float p2 = exp2f(sc[kj][2] - mrun);
      float p3 = exp2f(sc[kj][3] - mrun);
      rsum += (p0 + p1) + (p2 + p3);
      f16x4 ph;
      ph[0] = ((w >> (bb + 0)) & 1u) ? (_Float16)p0 : (_Float16)0.f;
      ph[1] = ((w >> (bb + 1)) & 1u) ? (_Float16)p1 : (_Float16)0.f;
      ph[2] = ((w >> (bb + 2)) & 1u) ? (_Float16)p2 : (_Float16)0.f;
      ph[3] = ((w >> (bb + 3)) & 1u) ? (_Float16)p3 : (_Float16)0.f;
      *(f16x4*)&Pt[(wid * 16 + tx) * 72 + kj * 16 + lg * 4] = ph;
    }
    rsum += __shfl_xor(rsum, 16, 64);
    rsum += __shfl_xor(rsum, 32, 64);
    lrun += rsum;

    __syncthreads();   // (c): P ready; Ms[kt&1] readers done

    if (kt + 2 < NKT) Ms[(kt & 1) * 256 + tid] = (unsigned short)nexth;

    // ---- PV: acc[q][d] += P[q][k] * Vt[d][k] (swizzled V reads) ----
#pragma unroll
    for (int ks = 0; ks < 2; ++ks) {
      f16x8 pa = *(const f16x8*)&Pt[(wid * 16 + tx) * 72 + ks * 32 + lg * 8];
#pragma unroll
      for (int n = 0; n < 8; ++n) {
        int dr = n * 16 + tx;
        f16x8 vb = *(const f16x8*)&Vts[dr * 64 + 8 * ((ks * 4 + lg) ^ vswz)];
        acc[n] = MFMA16F(pa, vb, acc[n]);
      }
    }
  }

  // ---- epilogue: out = acc / (0.9 * l) ----
#pragma unroll
  for (int r = 0; r < 4; ++r) {
    float lr = __shfl(lrun, (lane & 48) | (lg * 4 + r), 64);
    float inv = 1.0f / (0.9f * lr);
    int orow = wid * 16 + lg * 4 + r;
#pragma unroll
    for (int n = 0; n < 8; ++n)
      Oh[orow * DD + n * 16 + tx] = acc[n][r] * inv;
  }
}

// ============================================================================
// fallback (ws too small): R5/R6-style monolithic bf16 kernel, 512 threads
// ============================================================================
#define THREADS_FB 512
#define SMEM_SHORTS_FB 36864
__global__ __launch_bounds__(THREADS_FB) void pm_attn_fb(
    const float* __restrict__ Qg, const float* __restrict__ Kg,
    const float* __restrict__ Vg, const float* __restrict__ isf,
    float* __restrict__ Og)
{
  __shared__ __align__(16) short smem[SMEM_SHORTS_FB];
  short* const Khi = smem;
  short* const Klo = smem + 8704;
  short* const Vt  = smem + 17408;
  short* const Pts = smem + 26624;
  unsigned short* const Ms = (unsigned short*)(smem + 35840);

  const int tid  = threadIdx.x;
  const int lane = tid & 63;
  const int wid  = tid >> 6;
  const int lg   = lane >> 4;
  const int tx   = lane & 15;

  const int swz   = (blockIdx.x & 7) * 128 + (blockIdx.x >> 3);
  const int head  = swz >> 3;
  const int qbase = (swz & 7) * 128;

  const size_t hoff = (size_t)head * (SS * DD);
  const float* Qh = Qg + hoff + (size_t)qbase * DD;
  const float* Kh = Kg + hoff;
  const float* Vh = Vg + hoff;
  float*       Oh = Og + hoff + (size_t)qbase * DD;

  const int qrow = wid * 16 + tx;
  bf16x8 qhi[4], qlo[4];
#pragma unroll
  for (int ds = 0; ds < 4; ++ds) {
    const float* qp = Qh + qrow * DD + ds * 32 + lg * 8;
    float x[8];
    *(float4*)&x[0] = *(const float4*)qp;
    *(float4*)&x[4] = *(const float4*)(qp + 4);
#pragma unroll
    for (int e = 0; e < 8; ++e) {
      short h, l;
      split2(x[e], h, l);
      qhi[ds][e] = h;
      qlo[ds][e] = l;
    }
  }

  f32x4 acc[8];
#pragma unroll
  for (int n = 0; n < 8; ++n) acc[n] = (f32x4){0.f, 0.f, 0.f, 0.f};
  float mrun = -1e30f, lrun = 0.f;

  const uint32_t ctrbase = ((uint32_t)head << 20) |
                           ((uint32_t)(qbase + (tid >> 2)) << 10) |
                           (uint32_t)((tid & 3) * 16);
  Ms[tid]       = (unsigned short)maskhalf(ctrbase);
  Ms[512 + tid] = (unsigned short)maskhalf(ctrbase + 64u);

  const int vd = tid & 127;
  const int vq = tid >> 7;

  for (int kt = 0; kt < NKT; ++kt) {
    const float* Kt  = Kh + (size_t)kt * (TK * DD);
    const float* Vtg = Vh + (size_t)kt * (TK * DD);

    __syncthreads();
#pragma unroll
    for (int i = 0; i < 4; ++i) {
      int f = tid * 4 + i * 2048;
      int row = f >> 7, col = f & 127;
      float rsk = LOG2E * __builtin_amdgcn_rcpf(isf[kt * 64 + row]);
      float4 k4 = *(const float4*)(Kt + f);
      short h0, h1, h2, h3, l0, l1, l2, l3;
      split2(k4.x * rsk, h0, l0); split2(k4.y * rsk, h1, l1);
      split2(k4.z * rsk, h2, l2); split2(k4.w * rsk, h3, l3);
      *(uint2*)&Khi[row * 136 + col] = (uint2){pack2(h0, h1), pack2(h2, h3)};
      *(uint2*)&Klo[row * 136 + col] = (uint2){pack2(l0, l1), pack2(l2, l3)};
    }
#pragma unroll
    for (int j4 = 0; j4 < 4; ++j4) {
      int k0 = vq * 16 + j4 * 4;
      float a0 = Vtg[(k0 + 0) * DD + vd];
      float a1 = Vtg[(k0 + 1) * DD + vd];
      float a2 = Vtg[(k0 + 2) * DD + vd];
      float a3 = Vtg[(k0 + 3) * DD + vd];
      *(uint2*)&Vt[vd * 72 + k0] =
          (uint2){pack2(f2bf(a0), f2bf(a1)), pack2(f2bf(a2), f2bf(a3))};
    }
    __syncthreads();

    f32x4 sc[4];
#pragma unroll
    for (int kj = 0; kj < 4; ++kj) sc[kj] = (f32x4){0.f, 0.f, 0.f, 0.f};
#pragma unroll
    for (int ds = 0; ds < 4; ++ds) {
#pragma unroll
      for (int kj = 0; kj < 4; ++kj) {
        int off = (kj * 16 + tx) * 136 + ds * 32 + lg * 8;
        bf16x8 bhi = *(const bf16x8*)&Khi[off];
        bf16x8 blo = *(const bf16x8*)&Klo[off];
        sc[kj] = MFMA16B(bhi, qhi[ds], sc[kj]);
        sc[kj] = MFMA16B(bhi, qlo[ds], sc[kj]);
        sc[kj] = MFMA16B(blo, qhi[ds], sc[kj]);
      }
    }

    float pmax = sc[0][0];
#pragma unroll
    for (int kj = 0; kj < 4; ++kj)
#pragma unroll
      for (int r = 0; r < 4; ++r) pmax = fmaxf(pmax, sc[kj][r]);

    if (!__all(pmax <= mrun + DEFER_THR)) {
      float mt = fmaxf(pmax, __shfl_xor(pmax, 16, 64));
      mt = fmaxf(mt, __shfl_xor(mt, 32, 64));
      float mnew = fmaxf(mrun, mt);
      float corr = exp2f(mrun - mnew);
      lrun *= corr;
#pragma unroll
      for (int r = 0; r < 4; ++r) {
        float cr = __shfl(corr, (lane & 48) | (lg * 4 + r), 64);
#pragma unroll
        for (int n = 0; n < 8; ++n) acc[n][r] *= cr;
      }
      mrun = mnew;
    }

    uint2 ww = *(const uint2*)&Ms[(kt & 1) * 512 + (wid * 16 + tx) * 4];
    float rsum = 0.f;
#pragma unroll
    for (int kj = 0; kj < 4; ++kj) {
      uint32_t w = (kj < 2) ? ww.x : ww.y;
      int bb = (kj & 1) * 16 + lg * 4;
      float p0 = exp2f(sc[kj][0] - mrun);
      float p1 = exp2f(sc[kj][1] - mrun);
      float p2 = exp2f(sc[kj][2] - mrun);
      float p3 = exp2f(sc[kj][3] - mrun);
      rsum += (p0 + p1) + (p2 + p3);
      short b0 = ((w >> (bb + 0)) & 1u) ? f2bf(p0) : (short)0;
      short b1 = ((w >> (bb + 1)) & 1u) ? f2bf(p1) : (short)0;
      short b2 = ((w >> (bb + 2)) & 1u) ? f2bf(p2) : (short)0;
      short b3 = ((w >> (bb + 3)) & 1u) ? f2bf(p3) : (short)0;
      *(uint2*)&Pts[(wid * 16 + tx) * 72 + kj * 16 + lg * 4] =
          (uint2){pack2(b0, b1), pack2(b2, b3)};
    }
    rsum += __shfl_xor(rsum, 16, 64);
    rsum += __shfl_xor(rsum, 32, 64);
    lrun += rsum;

    uint32_t nexth = 0;
    if (kt + 2 < NKT) nexth = maskhalf(ctrbase + (uint32_t)((kt + 2) * 64));

    __syncthreads();

    if (kt + 2 < NKT) Ms[(kt & 1) * 512 + tid] = (unsigned short)nexth;

#pragma unroll
    for (int ks = 0; ks < 2; ++ks) {
      bf16x8 pa = *(const bf16x8*)&Pts[(wid * 16 + tx) * 72 + ks * 32 + lg * 8];
#pragma unroll
      for (int n = 0; n < 8; ++n) {
        bf16x8 vb = *(const bf16x8*)&Vt[(n * 16 + tx) * 72 + ks * 32 + lg * 8];
        acc[n] = MFMA16B(pa, vb, acc[n]);
      }
    }
  }

#pragma unroll
  for (int r = 0; r < 4; ++r) {
    float lr = __shfl(lrun, (lane & 48) | (lg * 4 + r), 64);
    float inv = 1.0f / (0.9f * lr);
    int orow = wid * 16 + lg * 4 + r;
#pragma unroll
    for (int n = 0; n < 8; ++n)
      Oh[orow * DD + n * 16 + tx] = acc[n][r] * inv;
  }
}

extern "C" void kernel_launch(void* const* d_in, const int* in_sizes, int n_in,
                              void* d_out, int out_size, void* d_ws, size_t ws_size,
                              hipStream_t stream) {
  const float* q   = (const float*)d_in[0];
  const float* k   = (const float*)d_in[1];
  const float* v   = (const float*)d_in[2];
  const float* isf = (const float*)d_in[3];

  if (ws_size >= PREP_BYTES) {
    pm_prep<<<dim3(NHEAD * NKT), dim3(256), 0, stream>>>(k, v, isf, (short*)d_ws);
    pm_attn<<<dim3(NBLK), dim3(THREADS), 0, stream>>>(
        q, (const short*)d_ws, (float*)d_out);
  } else {
    pm_attn_fb<<<dim3(NHEAD * 8), dim3(THREADS_FB), 0, stream>>>(
        q, k, v, isf, (float*)d_out);
  }
}

// Round 9
// 348.102 us; speedup vs baseline: 1.4167x; 1.0506x over previous
//
#include <hip/hip_runtime.h>
#include <hip/hip_bf16.h>
#include <stdint.h>

#define SS 1024
#define DD 128
#define TQ 64           // q rows per block (4 waves x 16)
#define TK 64           // kv cols per tile
#define NKT (SS/TK)     // 16
#define THREADS 256     // 4 waves
#define NBLK (128 * (SS/TQ))   // 2048
#define NHEAD 128
#define LOG2E 1.44269504088896340736f
#define DEFER_THR 11.5415603f   // 8 * log2e

// prep tile: Kf[64][128] fp16 (8-short-chunk swz) | Vt[128][64] fp16 (4-short-chunk swz)
#define TILE_SHORTS 16384
#define TILE_BYTES  32768
#define PREP_BYTES ((size_t)NHEAD * NKT * TILE_BYTES)   // 64 MiB

typedef _Float16 f16x8 __attribute__((ext_vector_type(8)));
typedef _Float16 f16x4 __attribute__((ext_vector_type(4)));
typedef short bf16x8 __attribute__((ext_vector_type(8)));
typedef float f32x4  __attribute__((ext_vector_type(4)));

// ---------------- threefry2x32, key = (0, 42) — bit-exact (R1) -------------
__device__ __forceinline__ uint32_t rotl32(uint32_t v, uint32_t s) {
  return __builtin_amdgcn_alignbit(v, v, 32u - s);
}
__device__ __forceinline__ uint32_t threefry_bits(uint32_t ctr) {
  const uint32_t K0 = 0u, K1 = 42u;
  const uint32_t K2 = K0 ^ K1 ^ 0x1BD11BDAu;
  uint32_t x0 = K0;
  uint32_t x1 = ctr + K1;
#define TF_RND(r) { x0 += x1; x1 = rotl32(x1, r); x1 ^= x0; }
  TF_RND(13u) TF_RND(15u) TF_RND(26u) TF_RND(6u)
  x0 += K1; x1 += K2 + 1u;
  TF_RND(17u) TF_RND(29u) TF_RND(16u) TF_RND(24u)
  x0 += K2; x1 += K0 + 2u;
  TF_RND(13u) TF_RND(15u) TF_RND(26u) TF_RND(6u)
  x0 += K0; x1 += K1 + 3u;
  TF_RND(17u) TF_RND(29u) TF_RND(16u) TF_RND(24u)
  x0 += K1; x1 += K2 + 4u;
  TF_RND(13u) TF_RND(15u) TF_RND(26u) TF_RND(6u)
  x0 += K2; x1 += K0 + 5u;
#undef TF_RND
  return x0 ^ x1;
}
// 16 keep-bits at element counter `base` (bit b: uniform < 0.9f)
__device__ __forceinline__ uint32_t maskhalf(uint32_t base) {
  uint32_t h = 0u;
#pragma unroll 4
  for (int b = 0; b < 16; ++b)
    h |= (threefry_bits(base + (uint32_t)b) < 0xE6666600u) ? (1u << b) : 0u;
  return h;
}

// ---------------- helpers ---------------------------------------------------
__device__ __forceinline__ short f2bf(float x) {
  return __builtin_bit_cast(short, __float2bfloat16(x));
}
__device__ __forceinline__ float bf2f(short b) {
  return __uint_as_float(((uint32_t)(uint16_t)b) << 16);
}
__device__ __forceinline__ uint32_t pack2(short a, short b) {
  return (uint32_t)(uint16_t)a | ((uint32_t)(uint16_t)b << 16);
}
__device__ __forceinline__ void split2(float x, short& hi, short& lo) {
  hi = f2bf(x);
  lo = f2bf(x - bf2f(hi));
}
// packed f32x2 -> f16x2 (RTZ), as raw u32 for fragment assembly
__device__ __forceinline__ uint32_t pkrtz(float a, float b) {
  return __builtin_bit_cast(uint32_t, __builtin_amdgcn_cvt_pkrtz(a, b));
}

#define MFMA_QK(A, B, C) __builtin_amdgcn_mfma_f32_16x16x32_f16(A, B, C, 0, 0, 0)
#define MFMA_PV(A, B, C) __builtin_amdgcn_mfma_f32_16x16x16f16(A, B, C, 0, 0, 0)
#define MFMA16B(A, B, C) __builtin_amdgcn_mfma_f32_16x16x32_bf16(A, B, C, 0, 0, 0)
#define EXP2(x) __builtin_amdgcn_exp2f(x)

// async global->LDS, 16B per lane (dest = wave-uniform base + lane*16)
__device__ __forceinline__ void gl_lds16(const void* g, void* lds) {
  auto gp = (const __attribute__((address_space(1))) uint32_t*)(uintptr_t)g;
  auto lp = (__attribute__((address_space(3))) uint32_t*)(uintptr_t)lds;
  __builtin_amdgcn_global_load_lds(gp, lp, 16, 0, 0);
}

// ============================================================================
// prepass: per (head, kt) build the 32KB image (fp16):
//   Kf[k][d]  scaled by log2e/isf[k]; 8-short chunks, slot = (d>>3)^(k&15)
//   Vt[d][k]  transposed;             4-short chunks, slot = (k>>2)^(d&15)
// ============================================================================
__global__ __launch_bounds__(256) void pm_prep(
    const float* __restrict__ Kg, const float* __restrict__ Vg,
    const float* __restrict__ isf, short* __restrict__ prep)
{
  __shared__ short lv[64 * 132];
  const int bid = blockIdx.x;          // head*16 + kt
  const int head = bid >> 4, kt = bid & 15;
  const int tid = threadIdx.x;
  const float* Kt  = Kg + ((size_t)head * SS + (size_t)kt * TK) * DD;
  const float* Vtg = Vg + ((size_t)head * SS + (size_t)kt * TK) * DD;
  short* tile = prep + (size_t)bid * TILE_SHORTS;

#pragma unroll
  for (int i = 0; i < 8; ++i) {
    int f = tid * 4 + i * 1024;        // 8192 fp32 elements
    int k = f >> 7, d = f & 127;
    float rsk = LOG2E * __builtin_amdgcn_rcpf(isf[kt * TK + k]);
    float4 k4 = *(const float4*)(Kt + f);
    f16x4 kh = { (_Float16)(k4.x * rsk), (_Float16)(k4.y * rsk),
                 (_Float16)(k4.z * rsk), (_Float16)(k4.w * rsk) };
    int idx = k * 128 + (d & 7) + 8 * ((d >> 3) ^ (k & 15));
    *(f16x4*)&tile[idx] = kh;
    // stage V fp16 [k][d] for transpose
    float4 v4 = *(const float4*)(Vtg + f);
    f16x4 vh = { (_Float16)v4.x, (_Float16)v4.y, (_Float16)v4.z, (_Float16)v4.w };
    *(f16x4*)&lv[k * 132 + d] = vh;
  }
  __syncthreads();
  // Vt[d][k]: thread owns d = tid>>1, slots s = (tid&1)*8 + j (j<8)
  {
    int d = tid >> 1;
    int s0 = (tid & 1) * 8;
#pragma unroll
    for (int j = 0; j < 8; ++j) {
      int s = s0 + j;
      int k0 = (s ^ (d & 15)) * 4;
      short tmp[4];
#pragma unroll
      for (int e = 0; e < 4; ++e) tmp[e] = lv[(k0 + e) * 132 + d];
      *(uint2*)&tile[8192 + d * 64 + s * 4] = *(uint2*)tmp;
    }
  }
}

// ============================================================================
// main fused kernel: fp16, reg-direct PV (16x16x16 MFMA), 2 barriers/kt
// LDS (shorts): Kf @0 (8192), Vt @8192 (8192), Ms u16[2][256] @16384
//   -> 16896 shorts = 33792 B -> 4 blocks/CU
// ============================================================================
#define SMEM_SHORTS 16896

__global__ __launch_bounds__(THREADS, 4) void pm_attn(
    const float* __restrict__ Qg, const short* __restrict__ prep,
    float* __restrict__ Og)
{
  __shared__ __align__(16) short smem[SMEM_SHORTS];
  unsigned short* const Ms = (unsigned short*)(smem + 16384);

  const int tid  = threadIdx.x;
  const int lane = tid & 63;
  const int wid  = tid >> 6;       // wave 0..3, owns q rows [wid*16, +16)
  const int lg   = lane >> 4;      // 0..3
  const int tx   = lane & 15;

  // XCD-aware swizzle: all 16 q-blocks of a head colocated on one XCD
  const int swz   = (blockIdx.x & 7) * (NBLK / 8) + (blockIdx.x >> 3);
  const int head  = swz >> 4;
  const int qbase = (swz & 15) * TQ;

  const size_t hoff = (size_t)head * (SS * DD);
  const float* Qh = Qg + hoff + (size_t)qbase * DD;
  float*       Oh = Og + hoff + (size_t)qbase * DD;

  // ---- Q fragments straight from global (row = wid*16+tx), fp16 ----
  const int qrow = wid * 16 + tx;
  f16x8 qf[4];
#pragma unroll
  for (int ds = 0; ds < 4; ++ds) {
    const float* qp = Qh + qrow * DD + ds * 32 + lg * 8;
    float x[8];
    *(float4*)&x[0] = *(const float4*)qp;
    *(float4*)&x[4] = *(const float4*)(qp + 4);
#pragma unroll
    for (int e = 0; e < 8; ++e) qf[ds][e] = (_Float16)x[e];
  }

  // ---- hoisted lane-constant LDS read bases (32-bit LDS pointers) ----
  const short* kb[4];                  // K: row tx*128, chunk (ds*4+lg)^tx
#pragma unroll
  for (int ds = 0; ds < 4; ++ds)
    kb[ds] = &smem[tx * 128 + (((ds * 4 + lg) ^ tx) << 3)];
  const short* vb[4];                  // V: row tx*64 (+n*16 rows via imm), chunk (kj*4+lg)^tx
#pragma unroll
  for (int kj = 0; kj < 4; ++kj)
    vb[kj] = &smem[8192 + tx * 64 + (((kj * 4 + lg) ^ tx) << 2)];

  f32x4 acc[8];
#pragma unroll
  for (int n = 0; n < 8; ++n) acc[n] = (f32x4){0.f, 0.f, 0.f, 0.f};
  float mrun = -1e30f, lpart = 0.f;

  // dropout ownership: thread t -> q row t>>2, 16-bit k-group t&3
  const uint32_t ctrbase = ((uint32_t)head << 20) |
                           ((uint32_t)(qbase + (tid >> 2)) << 10) |
                           (uint32_t)((tid & 3) * 16);
  Ms[tid]       = (unsigned short)maskhalf(ctrbase);          // tile 0
  Ms[256 + tid] = (unsigned short)maskhalf(ctrbase + 64u);    // tile 1
  uint32_t pending = 0;

  const char* gsrc0 = (const char*)prep + (size_t)(head * NKT) * TILE_BYTES
                      + wid * 1024 + lane * 16;
  char* const ldst0 = (char*)smem + wid * 1024;

  for (int kt = 0; kt < NKT; ++kt) {
    __syncthreads();   // (a): prev tile's LDS reads + Ms reads done

    // commit mask half-word for tile kt+1 (computed last iteration)
    if (kt >= 1 && kt + 1 < NKT)
      Ms[((kt + 1) & 1) * 256 + tid] = (unsigned short)pending;

    // ---- issue async 32KB tile DMA; drained at barrier (b) ----
    {
      const char* gs = gsrc0 + (size_t)kt * TILE_BYTES;
#pragma unroll
      for (int i = 0; i < 8; ++i)
        gl_lds16(gs + i * 4096, ldst0 + i * 4096);
    }

    // ---- threefry for tile kt+2 — hides the DMA latency ----
    if (kt + 2 < NKT) pending = maskhalf(ctrbase + (uint32_t)((kt + 2) * 64));

    __syncthreads();   // (b): K/V + Ms visible

    // ---- swapped QK^T (pre-scaled, log2 domain): lane owns q=tx ----
    f32x4 sc[4];
#pragma unroll
    for (int kj = 0; kj < 4; ++kj) sc[kj] = (f32x4){0.f, 0.f, 0.f, 0.f};
#pragma unroll
    for (int ds = 0; ds < 4; ++ds) {
      f16x8 qv = qf[ds];
#pragma unroll
      for (int kj = 0; kj < 4; ++kj) {
        f16x8 kf = *(const f16x8*)(kb[ds] + kj * 2048);
        sc[kj] = MFMA_QK(kf, qv, sc[kj]);
      }
    }

    // ---- online softmax (log2 domain), defer-max ----
    float pmax = sc[0][0];
#pragma unroll
    for (int kj = 0; kj < 4; ++kj)
#pragma unroll
      for (int r = 0; r < 4; ++r) pmax = fmaxf(pmax, sc[kj][r]);

    if (!__all(pmax <= mrun + DEFER_THR)) {
      float mt = fmaxf(pmax, __shfl_xor(pmax, 16, 64));
      mt = fmaxf(mt, __shfl_xor(mt, 32, 64));
      float mnew = fmaxf(mrun, mt);
      float corr = EXP2(mrun - mnew);
      lpart *= corr;
#pragma unroll
      for (int r = 0; r < 4; ++r) {
        float cr = __shfl(corr, (lane & 48) | (lg * 4 + r), 64);
#pragma unroll
        for (int n = 0; n < 8; ++n) acc[n][r] *= cr;
      }
      mrun = mnew;
    }

    // ---- per kj: exp2, mask, pack to regs, PV MFMA (no LDS round-trip) ----
    uint2 ww = *(const uint2*)&Ms[(kt & 1) * 256 + (wid * 16 + tx) * 4];
#pragma unroll
    for (int kj = 0; kj < 4; ++kj) {
      uint32_t wbits = (kj & 2) ? ww.y : ww.x;
      int bb = (kj & 1) * 16 + lg * 4;
      float p0 = EXP2(sc[kj][0] - mrun);
      float p1 = EXP2(sc[kj][1] - mrun);
      float p2 = EXP2(sc[kj][2] - mrun);
      float p3 = EXP2(sc[kj][3] - mrun);
      lpart += (p0 + p1) + (p2 + p3);
      float m0 = ((wbits >> (bb + 0)) & 1u) ? p0 : 0.f;
      float m1 = ((wbits >> (bb + 1)) & 1u) ? p1 : 0.f;
      float m2 = ((wbits >> (bb + 2)) & 1u) ? p2 : 0.f;
      float m3 = ((wbits >> (bb + 3)) & 1u) ? p3 : 0.f;
      uint2 pu = { pkrtz(m0, m1), pkrtz(m2, m3) };
      f16x4 pa = __builtin_bit_cast(f16x4, pu);
#pragma unroll
      for (int n = 0; n < 8; ++n) {
        f16x4 vv = *(const f16x4*)(vb[kj] + n * 1024);
        acc[n] = MFMA_PV(pa, vv, acc[n]);
      }
    }
  }

  // ---- epilogue: reduce l across lg groups, out = acc / (0.9 * l) ----
  lpart += __shfl_xor(lpart, 16, 64);
  lpart += __shfl_xor(lpart, 32, 64);
#pragma unroll
  for (int r = 0; r < 4; ++r) {
    float lr = __shfl(lpart, (lane & 48) | (lg * 4 + r), 64);
    float inv = 1.0f / (0.9f * lr);
    int orow = wid * 16 + lg * 4 + r;
#pragma unroll
    for (int n = 0; n < 8; ++n)
      Oh[orow * DD + n * 16 + tx] = acc[n][r] * inv;
  }
}

// ============================================================================
// fallback (ws too small): monolithic bf16 kernel (R7), 512 threads
// ============================================================================
#define THREADS_FB 512
#define SMEM_SHORTS_FB 36864
__global__ __launch_bounds__(THREADS_FB) void pm_attn_fb(
    const float* __restrict__ Qg, const float* __restrict__ Kg,
    const float* __restrict__ Vg, const float* __restrict__ isf,
    float* __restrict__ Og)
{
  __shared__ __align__(16) short smem[SMEM_SHORTS_FB];
  short* const Khi = smem;
  short* const Klo = smem + 8704;
  short* const Vt  = smem + 17408;
  short* const Pts = smem + 26624;
  unsigned short* const Ms = (unsigned short*)(smem + 35840);

  const int tid  = threadIdx.x;
  const int lane = tid & 63;
  const int wid  = tid >> 6;
  const int lg   = lane >> 4;
  const int tx   = lane & 15;

  const int swz   = (blockIdx.x & 7) * 128 + (blockIdx.x >> 3);
  const int head  = swz >> 3;
  const int qbase = (swz & 7) * 128;

  const size_t hoff = (size_t)head * (SS * DD);
  const float* Qh = Qg + hoff + (size_t)qbase * DD;
  const float* Kh = Kg + hoff;
  const float* Vh = Vg + hoff;
  float*       Oh = Og + hoff + (size_t)qbase * DD;

  const int qrow = wid * 16 + tx;
  bf16x8 qhi[4], qlo[4];
#pragma unroll
  for (int ds = 0; ds < 4; ++ds) {
    const float* qp = Qh + qrow * DD + ds * 32 + lg * 8;
    float x[8];
    *(float4*)&x[0] = *(const float4*)qp;
    *(float4*)&x[4] = *(const float4*)(qp + 4);
#pragma unroll
    for (int e = 0; e < 8; ++e) {
      short h, l;
      split2(x[e], h, l);
      qhi[ds][e] = h;
      qlo[ds][e] = l;
    }
  }

  f32x4 acc[8];
#pragma unroll
  for (int n = 0; n < 8; ++n) acc[n] = (f32x4){0.f, 0.f, 0.f, 0.f};
  float mrun = -1e30f, lrun = 0.f;

  const uint32_t ctrbase = ((uint32_t)head << 20) |
                           ((uint32_t)(qbase + (tid >> 2)) << 10) |
                           (uint32_t)((tid & 3) * 16);
  Ms[tid]       = (unsigned short)maskhalf(ctrbase);
  Ms[512 + tid] = (unsigned short)maskhalf(ctrbase + 64u);

  const int vd = tid & 127;
  const int vq = tid >> 7;

  for (int kt = 0; kt < NKT; ++kt) {
    const float* Kt  = Kh + (size_t)kt * (TK * DD);
    const float* Vtg = Vh + (size_t)kt * (TK * DD);

    __syncthreads();
#pragma unroll
    for (int i = 0; i < 4; ++i) {
      int f = tid * 4 + i * 2048;
      int row = f >> 7, col = f & 127;
      float rsk = LOG2E * __builtin_amdgcn_rcpf(isf[kt * 64 + row]);
      float4 k4 = *(const float4*)(Kt + f);
      short h0, h1, h2, h3, l0, l1, l2, l3;
      split2(k4.x * rsk, h0, l0); split2(k4.y * rsk, h1, l1);
      split2(k4.z * rsk, h2, l2); split2(k4.w * rsk, h3, l3);
      *(uint2*)&Khi[row * 136 + col] = (uint2){pack2(h0, h1), pack2(h2, h3)};
      *(uint2*)&Klo[row * 136 + col] = (uint2){pack2(l0, l1), pack2(l2, l3)};
    }
#pragma unroll
    for (int j4 = 0; j4 < 4; ++j4) {
      int k0 = vq * 16 + j4 * 4;
      float a0 = Vtg[(k0 + 0) * DD + vd];
      float a1 = Vtg[(k0 + 1) * DD + vd];
      float a2 = Vtg[(k0 + 2) * DD + vd];
      float a3 = Vtg[(k0 + 3) * DD + vd];
      *(uint2*)&Vt[vd * 72 + k0] =
          (uint2){pack2(f2bf(a0), f2bf(a1)), pack2(f2bf(a2), f2bf(a3))};
    }
    __syncthreads();

    f32x4 sc[4];
#pragma unroll
    for (int kj = 0; kj < 4; ++kj) sc[kj] = (f32x4){0.f, 0.f, 0.f, 0.f};
#pragma unroll
    for (int ds = 0; ds < 4; ++ds) {
#pragma unroll
      for (int kj = 0; kj < 4; ++kj) {
        int off = (kj * 16 + tx) * 136 + ds * 32 + lg * 8;
        bf16x8 bhi = *(const bf16x8*)&Khi[off];
        bf16x8 blo = *(const bf16x8*)&Klo[off];
        sc[kj] = MFMA16B(bhi, qhi[ds], sc[kj]);
        sc[kj] = MFMA16B(bhi, qlo[ds], sc[kj]);
        sc[kj] = MFMA16B(blo, qhi[ds], sc[kj]);
      }
    }

    float pmax = sc[0][0];
#pragma unroll
    for (int kj = 0; kj < 4; ++kj)
#pragma unroll
      for (int r = 0; r < 4; ++r) pmax = fmaxf(pmax, sc[kj][r]);

    if (!__all(pmax <= mrun + DEFER_THR)) {
      float mt = fmaxf(pmax, __shfl_xor(pmax, 16, 64));
      mt = fmaxf(mt, __shfl_xor(mt, 32, 64));
      float mnew = fmaxf(mrun, mt);
      float corr = EXP2(mrun - mnew);
      lrun *= corr;
#pragma unroll
      for (int r = 0; r < 4; ++r) {
        float cr = __shfl(corr, (lane & 48) | (lg * 4 + r), 64);
#pragma unroll
        for (int n = 0; n < 8; ++n) acc[n][r] *= cr;
      }
      mrun = mnew;
    }

    uint2 ww = *(const uint2*)&Ms[(kt & 1) * 512 + (wid * 16 + tx) * 4];
    float rsum = 0.f;
#pragma unroll
    for (int kj = 0; kj < 4; ++kj) {
      uint32_t w = (kj < 2) ? ww.x : ww.y;
      int bb = (kj & 1) * 16 + lg * 4;
      float p0 = EXP2(sc[kj][0] - mrun);
      float p1 = EXP2(sc[kj][1] - mrun);
      float p2 = EXP2(sc[kj][2] - mrun);
      float p3 = EXP2(sc[kj][3] - mrun);
      rsum += (p0 + p1) + (p2 + p3);
      short b0 = ((w >> (bb + 0)) & 1u) ? f2bf(p0) : (short)0;
      short b1 = ((w >> (bb + 1)) & 1u) ? f2bf(p1) : (short)0;
      short b2 = ((w >> (bb + 2)) & 1u) ? f2bf(p2) : (short)0;
      short b3 = ((w >> (bb + 3)) & 1u) ? f2bf(p3) : (short)0;
      *(uint2*)&Pts[(wid * 16 + tx) * 72 + kj * 16 + lg * 4] =
          (uint2){pack2(b0, b1), pack2(b2, b3)};
    }
    rsum += __shfl_xor(rsum, 16, 64);
    rsum += __shfl_xor(rsum, 32, 64);
    lrun += rsum;

    uint32_t nexth = 0;
    if (kt + 2 < NKT) nexth = maskhalf(ctrbase + (uint32_t)((kt + 2) * 64));

    __syncthreads();

    if (kt + 2 < NKT) Ms[(kt & 1) * 512 + tid] = (unsigned short)nexth;

#pragma unroll
    for (int ks = 0; ks < 2; ++ks) {
      bf16x8 pa = *(const bf16x8*)&Pts[(wid * 16 + tx) * 72 + ks * 32 + lg * 8];
#pragma unroll
      for (int n = 0; n < 8; ++n) {
        bf16x8 vbv = *(const bf16x8*)&Vt[(n * 16 + tx) * 72 + ks * 32 + lg * 8];
        acc[n] = MFMA16B(pa, vbv, acc[n]);
      }
    }
  }

#pragma unroll
  for (int r = 0; r < 4; ++r) {
    float lr = __shfl(lrun, (lane & 48) | (lg * 4 + r), 64);
    float inv = 1.0f / (0.9f * lr);
    int orow = wid * 16 + lg * 4 + r;
#pragma unroll
    for (int n = 0; n < 8; ++n)
      Oh[orow * DD + n * 16 + tx] = acc[n][r] * inv;
  }
}

extern "C" void kernel_launch(void* const* d_in, const int* in_sizes, int n_in,
                              void* d_out, int out_size, void* d_ws, size_t ws_size,
                              hipStream_t stream) {
  const float* q   = (const float*)d_in[0];
  const float* k   = (const float*)d_in[1];
  const float* v   = (const float*)d_in[2];
  const float* isf = (const float*)d_in[3];

  if (ws_size >= PREP_BYTES) {
    pm_prep<<<dim3(NHEAD * NKT), dim3(256), 0, stream>>>(k, v, isf, (short*)d_ws);
    pm_attn<<<dim3(NBLK), dim3(THREADS), 0, stream>>>(
        q, (const short*)d_ws, (float*)d_out);
  } else {
    pm_attn_fb<<<dim3(NHEAD * 8), dim3(THREADS_FB), 0, stream>>>(
        q, k, v, isf, (float*)d_out);
  }
}